// Round 1
// baseline (5613.911 us; speedup 1.0000x reference)
//
#include <hip/hip_runtime.h>
#include <hip/hip_bf16.h>
#include <math.h>

#define B_ 4
#define M_ 72
#define E_ 24
#define R_ 552
#define L_ 1024
#define H_ 1024
#define A_ 16
#define EMB_ 768
#define BLK_ 64
#define OUT_ 768
#define NC_ 97
#define N_ (B_*R_)        // 2208
#define K2H_ (2*H_)       // 2048
#define KB_ (EMB_/BLK_)   // 12

// ---------------- pooling: ent_emb (logsumexp) + amean ----------------
__global__ void k_pool(const float* __restrict__ ent_lhs,  // B,M,H
                       const float* __restrict__ attn,     // B,A,M,L
                       const int*   __restrict__ labels,   // B,M
                       float* __restrict__ ent_emb,        // B,E,H
                       float* __restrict__ amean)          // B,E,A,L
{
    int b = blockIdx.x / E_;
    int e = blockIdx.x % E_;
    __shared__ int mlist[M_];
    __shared__ int mcount;
    if (threadIdx.x == 0) {
        int c = 0;
        for (int m = 0; m < M_; ++m)
            if (labels[b*M_ + m] == e) mlist[c++] = m;
        mcount = c;
    }
    __syncthreads();
    int cnt = mcount;

    for (int h = threadIdx.x; h < H_; h += blockDim.x) {
        float out = 0.f;
        if (cnt > 0) {
            float mx = -INFINITY;
            for (int q = 0; q < cnt; ++q)
                mx = fmaxf(mx, ent_lhs[(size_t)(b*M_ + mlist[q])*H_ + h]);
            float s = 0.f;
            for (int q = 0; q < cnt; ++q)
                s += expf(ent_lhs[(size_t)(b*M_ + mlist[q])*H_ + h] - mx);
            out = logf(s) + mx;
        }
        ent_emb[(size_t)(b*E_ + e)*H_ + h] = out;
    }

    float inv = (cnt > 0) ? (1.f / (float)cnt) : 0.f;
    for (int c = threadIdx.x; c < A_*L_; c += blockDim.x) {
        int a = c / L_, l = c % L_;
        float s = 0.f;
        for (int q = 0; q < cnt; ++q)
            s += attn[((size_t)(b*A_ + a)*M_ + mlist[q])*L_ + l];
        amean[((size_t)(b*E_ + e)*A_ + a)*L_ + l] = s * inv;
    }
}

// ---------------- ht_attn: normalized head*tail attention ----------------
__global__ void k_htattn(const float* __restrict__ amean,   // B,E,A,L
                         const int*   __restrict__ hts,     // B,R,2
                         float* __restrict__ ht_attn)       // B,R,L
{
    int br = blockIdx.x;            // b*R + r
    int b  = br / R_;
    int hh = hts[br*2 + 0], tt = hts[br*2 + 1];
    const float* pa = amean + (size_t)(b*E_ + hh)*A_*L_;
    const float* pb = amean + (size_t)(b*E_ + tt)*A_*L_;

    float vals[L_/256];
    float partial = 0.f;
    for (int i = 0, l = threadIdx.x; l < L_; l += 256, ++i) {
        float s = 0.f;
        #pragma unroll
        for (int a = 0; a < A_; ++a)
            s += pa[(size_t)a*L_ + l] * pb[(size_t)a*L_ + l];
        s *= (1.f/(float)A_);
        vals[i] = s;
        partial += s;
    }
    __shared__ float red[256];
    red[threadIdx.x] = partial;
    __syncthreads();
    for (int st = 128; st > 0; st >>= 1) {
        if (threadIdx.x < st) red[threadIdx.x] += red[threadIdx.x + st];
        __syncthreads();
    }
    float norm = 1.f / (red[0] + 1e-5f);
    for (int i = 0, l = threadIdx.x; l < L_; l += 256, ++i)
        ht_attn[(size_t)br*L_ + l] = vals[i] * norm;
}

// ---------------- rel[b,r,d] = sum_l seq[b,l,d] * w[b,r,l] ----------------
// 8 r-rows per block, 256 d-columns per block
__global__ void k_rel(const float* __restrict__ seq,   // B,L,H
                      const float* __restrict__ w,     // B,R,L
                      float* __restrict__ rel)         // B,R,H
{
    int d   = blockIdx.x * 256 + threadIdx.x;
    int grp = blockIdx.y;                 // b*(R/8) + rg
    int b   = grp / (R_/8);
    int r0  = (grp % (R_/8)) * 8;
    __shared__ float ws[8][256];
    float acc[8] = {0,0,0,0,0,0,0,0};
    const float* sb = seq + (size_t)b*L_*H_;
    for (int l0 = 0; l0 < L_; l0 += 256) {
        __syncthreads();
        #pragma unroll
        for (int j = 0; j < 8; ++j)
            ws[j][threadIdx.x] = w[(size_t)(b*R_ + r0 + j)*L_ + l0 + threadIdx.x];
        __syncthreads();
        for (int l = 0; l < 256; ++l) {
            float s = sb[(size_t)(l0 + l)*H_ + d];
            #pragma unroll
            for (int j = 0; j < 8; ++j) acc[j] += s * ws[j][l];
        }
    }
    #pragma unroll
    for (int j = 0; j < 8; ++j)
        rel[(size_t)(b*R_ + r0 + j)*H_ + d] = acc[j];
}

// ---------------- gather + concat: hcat/tcat (N x 2048) ----------------
__global__ void k_concat(const float* __restrict__ ent_emb, // B,E,H
                         const float* __restrict__ rel,     // N,H
                         const int*   __restrict__ hts,     // B,R,2
                         float* __restrict__ hcat,
                         float* __restrict__ tcat)
{
    int n = blockIdx.x;
    int b = n / R_;
    int hh = hts[n*2 + 0], tt = hts[n*2 + 1];
    const float* eh = ent_emb + (size_t)(b*E_ + hh)*H_;
    const float* et = ent_emb + (size_t)(b*E_ + tt)*H_;
    const float* rr = rel + (size_t)n*H_;
    float* ph = hcat + (size_t)n*K2H_;
    float* pt = tcat + (size_t)n*K2H_;
    for (int c = threadIdx.x; c < H_; c += blockDim.x) {
        float rv = rr[c];
        ph[c] = eh[c]; ph[H_ + c] = rv;
        pt[c] = et[c]; pt[H_ + c] = rv;
    }
}

// ---------------- projection GEMM: C = tanh(A @ W + b), A: N x 2048, W: 2048 x 768 ----
__global__ void k_proj(const float* __restrict__ Am,
                       const float* __restrict__ W,
                       const float* __restrict__ bias,
                       float* __restrict__ C)
{
    int m0 = blockIdx.x * 64;
    int n0 = blockIdx.y * 64;
    int tx = threadIdx.x % 16, ty = threadIdx.x / 16;
    __shared__ float a_s[64][68];
    __shared__ float w_s[64][68];
    float acc[4][4] = {};
    for (int k0 = 0; k0 < K2H_; k0 += 64) {
        __syncthreads();
        for (int t = threadIdx.x; t < 64*64; t += 256) {
            int rr = t >> 6, cc = t & 63;
            int gr = m0 + rr;
            a_s[rr][cc] = (gr < N_) ? Am[(size_t)gr*K2H_ + k0 + cc] : 0.f;
            w_s[rr][cc] = W[(size_t)(k0 + rr)*OUT_ + n0 + cc];
        }
        __syncthreads();
        for (int kk = 0; kk < 64; ++kk) {
            float av[4];
            #pragma unroll
            for (int u = 0; u < 4; ++u) av[u] = a_s[ty*4 + u][kk];
            const float4 wv = *reinterpret_cast<const float4*>(&w_s[kk][tx*4]);
            #pragma unroll
            for (int u = 0; u < 4; ++u) {
                acc[u][0] += av[u]*wv.x; acc[u][1] += av[u]*wv.y;
                acc[u][2] += av[u]*wv.z; acc[u][3] += av[u]*wv.w;
            }
        }
    }
    #pragma unroll
    for (int u = 0; u < 4; ++u) {
        int gr = m0 + ty*4 + u;
        if (gr < N_) {
            #pragma unroll
            for (int v = 0; v < 4; ++v) {
                int gc = n0 + tx*4 + v;
                C[(size_t)gr*OUT_ + gc] = tanhf(acc[u][v] + bias[gc]);
            }
        }
    }
}

// ---------------- bilinear GEMM: embeds = (hs ⊗blk ts) @ W_bil + b ----------------
// embeds[n,o] = sum_{k,i,j} hs[n,k*64+i]*ts[n,k*64+j]*Wb[(k*64+i)*64+j, o]
__global__ void k_bilinear(const float* __restrict__ hsp,  // N x EMB
                           const float* __restrict__ tsp,  // N x EMB
                           const float* __restrict__ Wb,   // (EMB*BLK) x OUT
                           const float* __restrict__ bias, // OUT
                           float* __restrict__ embeds)     // N x OUT
{
    int m0 = blockIdx.x * 64;
    int n0 = blockIdx.y * 64;
    int tx = threadIdx.x % 16, ty = threadIdx.x / 16;
    __shared__ float hs_s[64][68];
    __shared__ float ts_s[64][68];
    __shared__ float w_s[64][68];
    float acc[4][4] = {};
    for (int k = 0; k < KB_; ++k) {
        __syncthreads();
        for (int t = threadIdx.x; t < 64*64; t += 256) {
            int rr = t >> 6, cc = t & 63;
            int gr = m0 + rr;
            hs_s[rr][cc] = (gr < N_) ? hsp[(size_t)gr*EMB_ + k*64 + cc] : 0.f;
            ts_s[rr][cc] = (gr < N_) ? tsp[(size_t)gr*EMB_ + k*64 + cc] : 0.f;
        }
        __syncthreads();
        for (int i = 0; i < 64; ++i) {
            __syncthreads();
            for (int t = threadIdx.x; t < 64*64; t += 256) {
                int jj = t >> 6, cc = t & 63;
                w_s[jj][cc] = Wb[((size_t)(k*64 + i)*64 + jj)*OUT_ + n0 + cc];
            }
            __syncthreads();
            float hv[4];
            #pragma unroll
            for (int u = 0; u < 4; ++u) hv[u] = hs_s[ty*4 + u][i];
            for (int j4 = 0; j4 < 64; j4 += 4) {
                float4 tv[4];
                #pragma unroll
                for (int u = 0; u < 4; ++u)
                    tv[u] = *reinterpret_cast<const float4*>(&ts_s[ty*4 + u][j4]);
                #pragma unroll
                for (int jj = 0; jj < 4; ++jj) {
                    const float4 wv = *reinterpret_cast<const float4*>(&w_s[j4 + jj][tx*4]);
                    #pragma unroll
                    for (int u = 0; u < 4; ++u) {
                        float a = hv[u] * ((const float*)&tv[u])[jj];
                        acc[u][0] += a*wv.x; acc[u][1] += a*wv.y;
                        acc[u][2] += a*wv.z; acc[u][3] += a*wv.w;
                    }
                }
            }
        }
    }
    #pragma unroll
    for (int u = 0; u < 4; ++u) {
        int gr = m0 + ty*4 + u;
        if (gr < N_) {
            #pragma unroll
            for (int v = 0; v < 4; ++v) {
                int gc = n0 + tx*4 + v;
                embeds[(size_t)gr*OUT_ + gc] = acc[u][v] + bias[gc];
            }
        }
    }
}

// ---------------- class + binary logits ----------------
__global__ void k_logits(const float* __restrict__ embeds,
                         const float* __restrict__ Wc, const float* __restrict__ bc,
                         const float* __restrict__ Wbn, const float* __restrict__ bbn,
                         float* __restrict__ cls, float* __restrict__ bin)
{
    int n = blockIdx.x;
    __shared__ float row[OUT_];
    for (int o = threadIdx.x; o < OUT_; o += blockDim.x)
        row[o] = embeds[(size_t)n*OUT_ + o];
    __syncthreads();
    for (int c = threadIdx.x; c < NC_ + 1; c += blockDim.x) {
        if (c < NC_) {
            float acc = bc[c];
            for (int o = 0; o < OUT_; ++o) acc += row[o] * Wc[(size_t)o*NC_ + c];
            cls[(size_t)n*NC_ + c] = acc;
        } else {
            float acc = bbn[0];
            for (int o = 0; o < OUT_; ++o) acc += row[o] * Wbn[o];
            bin[n] = acc;
        }
    }
}

extern "C" void kernel_launch(void* const* d_in, const int* in_sizes, int n_in,
                              void* d_out, int out_size, void* d_ws, size_t ws_size,
                              hipStream_t stream) {
    const float* seq_lhs = (const float*)d_in[0];
    const float* ent_lhs = (const float*)d_in[1];
    const float* attn    = (const float*)d_in[2];
    const int*   labels  = (const int*)d_in[3];
    const int*   hts     = (const int*)d_in[4];
    const float* W_head  = (const float*)d_in[5];
    const float* b_head  = (const float*)d_in[6];
    const float* W_tail  = (const float*)d_in[7];
    const float* b_tail  = (const float*)d_in[8];
    const float* W_bil   = (const float*)d_in[9];
    const float* b_bil   = (const float*)d_in[10];
    const float* W_cls   = (const float*)d_in[11];
    const float* b_cls   = (const float*)d_in[12];
    const float* W_bin   = (const float*)d_in[13];
    const float* b_bin   = (const float*)d_in[14];

    float* out_embeds = (float*)d_out;                       // N x OUT
    float* out_cls    = out_embeds + (size_t)N_*OUT_;        // N x NC
    float* out_bin    = out_cls + (size_t)N_*NC_;            // N

    float* ws = (float*)d_ws;
    float* ent_emb = ws;                                  size_t off = (size_t)B_*E_*H_;
    float* amean   = ws + off;                            off += (size_t)B_*E_*A_*L_;
    float* ht_attn = ws + off;                            off += (size_t)B_*R_*L_;
    float* rel     = ws + off;                            off += (size_t)N_*H_;
    float* hcat    = ws + off;                            off += (size_t)N_*K2H_;
    float* tcat    = ws + off;                            off += (size_t)N_*K2H_;
    float* hsp     = ws + off;                            off += (size_t)N_*EMB_;
    float* tsp     = ws + off;                            off += (size_t)N_*EMB_;

    k_pool<<<B_*E_, 256, 0, stream>>>(ent_lhs, attn, labels, ent_emb, amean);
    k_htattn<<<B_*R_, 256, 0, stream>>>(amean, hts, ht_attn);
    k_rel<<<dim3(H_/256, B_*(R_/8)), 256, 0, stream>>>(seq_lhs, ht_attn, rel);
    k_concat<<<N_, 256, 0, stream>>>(ent_emb, rel, hts, hcat, tcat);
    dim3 pgrid((N_ + 63)/64, OUT_/64);
    k_proj<<<pgrid, 256, 0, stream>>>(hcat, W_head, b_head, hsp);
    k_proj<<<pgrid, 256, 0, stream>>>(tcat, W_tail, b_tail, tsp);
    k_bilinear<<<pgrid, 256, 0, stream>>>(hsp, tsp, W_bil, b_bil, out_embeds);
    k_logits<<<N_, 128, 0, stream>>>(out_embeds, W_cls, b_cls, W_bin, b_bin,
                                     out_cls, out_bin);
}

// Round 2
// 1315.727 us; speedup vs baseline: 4.2668x; 4.2668x over previous
//
#include <hip/hip_runtime.h>
#include <hip/hip_bf16.h>
#include <math.h>
#include <stdint.h>

#define B_ 4
#define M_ 72
#define E_ 24
#define R_ 552
#define L_ 1024
#define H_ 1024
#define A_ 16
#define EMB_ 768
#define BLK_ 64
#define OUT_ 768
#define NC_ 97
#define N_ (B_*R_)        // 2208
#define NPAD_ 2304        // padded rows for bf16 hs/ts buffers
#define K2H_ (2*H_)       // 2048
#define KB_ (EMB_/BLK_)   // 12
#define KTOT_ (EMB_*BLK_) // 49152

typedef short s16x8 __attribute__((ext_vector_type(8)));
typedef float f32x4 __attribute__((ext_vector_type(4)));
typedef uint32_t u32x4 __attribute__((ext_vector_type(4)));

__device__ __forceinline__ uint32_t pkbf16(float lo, float hi) {
    uint32_t r;
    asm("v_cvt_pk_bf16_f32 %0, %1, %2" : "=v"(r) : "v"(lo), "v"(hi));
    return r;
}
__device__ __forceinline__ unsigned short f2bf(float f) {
    uint32_t u = __builtin_bit_cast(uint32_t, f);
    uint32_t r = (u + 0x7fffu + ((u >> 16) & 1u)) >> 16;
    return (unsigned short)r;
}
__device__ __forceinline__ void gload_lds16(const void* g, void* l) {
    __builtin_amdgcn_global_load_lds(
        (const __attribute__((address_space(1))) unsigned int*)g,
        (__attribute__((address_space(3))) unsigned int*)l, 16, 0, 0);
}

// ---------------- pooling: ent_emb (logsumexp) + amean ----------------
__global__ void k_pool(const float* __restrict__ ent_lhs,  // B,M,H
                       const float* __restrict__ attn,     // B,A,M,L
                       const int*   __restrict__ labels,   // B,M
                       float* __restrict__ ent_emb,        // B,E,H
                       float* __restrict__ amean)          // B,E,A,L
{
    int b = blockIdx.x / E_;
    int e = blockIdx.x % E_;
    __shared__ int mlist[M_];
    __shared__ int mcount;
    if (threadIdx.x == 0) {
        int c = 0;
        for (int m = 0; m < M_; ++m)
            if (labels[b*M_ + m] == e) mlist[c++] = m;
        mcount = c;
    }
    __syncthreads();
    int cnt = mcount;

    for (int h = threadIdx.x; h < H_; h += blockDim.x) {
        float out = 0.f;
        if (cnt > 0) {
            float mx = -INFINITY;
            for (int q = 0; q < cnt; ++q)
                mx = fmaxf(mx, ent_lhs[(size_t)(b*M_ + mlist[q])*H_ + h]);
            float s = 0.f;
            for (int q = 0; q < cnt; ++q)
                s += expf(ent_lhs[(size_t)(b*M_ + mlist[q])*H_ + h] - mx);
            out = logf(s) + mx;
        }
        ent_emb[(size_t)(b*E_ + e)*H_ + h] = out;
    }

    float inv = (cnt > 0) ? (1.f / (float)cnt) : 0.f;
    for (int c = threadIdx.x; c < A_*L_; c += blockDim.x) {
        int a = c / L_, l = c % L_;
        float s = 0.f;
        for (int q = 0; q < cnt; ++q)
            s += attn[((size_t)(b*A_ + a)*M_ + mlist[q])*L_ + l];
        amean[((size_t)(b*E_ + e)*A_ + a)*L_ + l] = s * inv;
    }
}

// ---------------- ht_attn ----------------
__global__ void k_htattn(const float* __restrict__ amean,   // B,E,A,L
                         const int*   __restrict__ hts,     // B,R,2
                         float* __restrict__ ht_attn)       // B,R,L
{
    int br = blockIdx.x;
    int b  = br / R_;
    int hh = hts[br*2 + 0], tt = hts[br*2 + 1];
    const float* pa = amean + (size_t)(b*E_ + hh)*A_*L_;
    const float* pb = amean + (size_t)(b*E_ + tt)*A_*L_;

    float vals[L_/256];
    float partial = 0.f;
    for (int i = 0, l = threadIdx.x; l < L_; l += 256, ++i) {
        float s = 0.f;
        #pragma unroll
        for (int a = 0; a < A_; ++a)
            s += pa[(size_t)a*L_ + l] * pb[(size_t)a*L_ + l];
        s *= (1.f/(float)A_);
        vals[i] = s;
        partial += s;
    }
    __shared__ float red[256];
    red[threadIdx.x] = partial;
    __syncthreads();
    for (int st = 128; st > 0; st >>= 1) {
        if (threadIdx.x < st) red[threadIdx.x] += red[threadIdx.x + st];
        __syncthreads();
    }
    float norm = 1.f / (red[0] + 1e-5f);
    for (int i = 0, l = threadIdx.x; l < L_; l += 256, ++i)
        ht_attn[(size_t)br*L_ + l] = vals[i] * norm;
}

// ---------------- rel ----------------
__global__ void k_rel(const float* __restrict__ seq,   // B,L,H
                      const float* __restrict__ w,     // B,R,L
                      float* __restrict__ rel)         // B,R,H
{
    int d   = blockIdx.x * 256 + threadIdx.x;
    int grp = blockIdx.y;
    int b   = grp / (R_/8);
    int r0  = (grp % (R_/8)) * 8;
    __shared__ float ws[8][256];
    float acc[8] = {0,0,0,0,0,0,0,0};
    const float* sb = seq + (size_t)b*L_*H_;
    for (int l0 = 0; l0 < L_; l0 += 256) {
        __syncthreads();
        #pragma unroll
        for (int j = 0; j < 8; ++j)
            ws[j][threadIdx.x] = w[(size_t)(b*R_ + r0 + j)*L_ + l0 + threadIdx.x];
        __syncthreads();
        for (int l = 0; l < 256; ++l) {
            float s = sb[(size_t)(l0 + l)*H_ + d];
            #pragma unroll
            for (int j = 0; j < 8; ++j) acc[j] += s * ws[j][l];
        }
    }
    #pragma unroll
    for (int j = 0; j < 8; ++j)
        rel[(size_t)(b*R_ + r0 + j)*H_ + d] = acc[j];
}

// ---------------- proj (fused gather-concat): C = bf16(tanh(A @ W + b)) ----------------
__global__ void k_proj(const float* __restrict__ ent_emb, // B,E,H
                       const float* __restrict__ rel,     // N,H
                       const int*   __restrict__ hts,     // B,R,2
                       int which,
                       const float* __restrict__ W,
                       const float* __restrict__ bias,
                       unsigned short* __restrict__ C)    // NPAD x EMB (bf16)
{
    int m0 = blockIdx.x * 64;
    int n0 = blockIdx.y * 64;
    int tx = threadIdx.x % 16, ty = threadIdx.x / 16;
    __shared__ float a_s[64][68];
    __shared__ float w_s[64][68];
    __shared__ int eidx[64];
    if (threadIdx.x < 64) {
        int n = m0 + threadIdx.x;
        eidx[threadIdx.x] = (n < N_) ? ((n / R_)*E_ + hts[n*2 + which]) : 0;
    }
    float acc[4][4] = {};
    for (int k0 = 0; k0 < K2H_; k0 += 64) {
        __syncthreads();
        for (int t = threadIdx.x; t < 64*64; t += 256) {
            int rr = t >> 6, cc = t & 63;
            int n = m0 + rr;
            int c = k0 + cc;
            float v = 0.f;
            if (n < N_)
                v = (c < H_) ? ent_emb[(size_t)eidx[rr]*H_ + c]
                             : rel[(size_t)n*H_ + (c - H_)];
            a_s[rr][cc] = v;
            w_s[rr][cc] = W[(size_t)(k0 + rr)*OUT_ + n0 + cc];
        }
        __syncthreads();
        for (int kk = 0; kk < 64; ++kk) {
            float av[4];
            #pragma unroll
            for (int u = 0; u < 4; ++u) av[u] = a_s[ty*4 + u][kk];
            const float4 wv = *reinterpret_cast<const float4*>(&w_s[kk][tx*4]);
            #pragma unroll
            for (int u = 0; u < 4; ++u) {
                acc[u][0] += av[u]*wv.x; acc[u][1] += av[u]*wv.y;
                acc[u][2] += av[u]*wv.z; acc[u][3] += av[u]*wv.w;
            }
        }
    }
    #pragma unroll
    for (int u = 0; u < 4; ++u) {
        int gr = m0 + ty*4 + u;
        if (gr < N_) {
            #pragma unroll
            for (int v = 0; v < 4; ++v) {
                int gc = n0 + tx*4 + v;
                C[(size_t)gr*EMB_ + gc] = f2bf(tanhf(acc[u][v] + bias[gc]));
            }
        }
    }
}

// ---------------- W_bil f32 [49152][768] -> Wt bf16 [768][49152] ----------------
__global__ void k_cvtW(const float* __restrict__ W, unsigned short* __restrict__ Wt)
{
    __shared__ unsigned short t[64][72];
    int k0 = blockIdx.x * 64, o0 = blockIdx.y * 64;
    #pragma unroll
    for (int p = 0; p < 16; ++p) {
        int idx = p*256 + threadIdx.x;
        int r = idx >> 6, c = idx & 63;          // r: k-local, c: o-local
        t[c][r] = f2bf(W[(size_t)(k0 + r)*OUT_ + o0 + c]);
    }
    __syncthreads();
    #pragma unroll
    for (int p = 0; p < 16; ++p) {
        int idx = p*256 + threadIdx.x;
        int r = idx >> 6, c = idx & 63;          // r: o-local, c: k-local
        Wt[(size_t)(o0 + r)*KTOT_ + k0 + c] = t[r][c];
    }
}

// ---------------- embeds = bias (init before atomics) ----------------
__global__ void k_bias_init(const float* __restrict__ bias, float* __restrict__ embeds)
{
    int idx = blockIdx.x * 256 + threadIdx.x;
    if (idx < N_*OUT_) embeds[idx] = bias[idx % OUT_];
}

// ---------------- bilinear MFMA GEMM ----------------
// grid: 18 mb x 3 ob x 12 kb = 648 blocks, 256 threads (4 waves 2m x 2o)
// BM=128, BN=256; wave tile 64x128 (Fm=4 x Fo=8), K per block = 4096 (one kb)
__global__ __launch_bounds__(256, 2)
void k_bilinear_mfma(const unsigned short* __restrict__ hsp,  // NPAD x 768 bf16
                     const unsigned short* __restrict__ tsp,  // NPAD x 768 bf16
                     const unsigned short* __restrict__ Wt,   // 768 x 49152 bf16
                     float* __restrict__ embeds)              // N x 768 (atomic +=)
{
    int bid = blockIdx.x;
    int kb = bid % KB_;
    int rest = bid / KB_;
    int ob = rest % 3;
    int mb = rest / 3;
    int m0 = mb * 128, o0 = ob * 256;
    int tid = threadIdx.x;
    int lane = tid & 63, wid = tid >> 6;
    int wr = wid >> 1, wc = wid & 1;

    __shared__ __align__(16) unsigned short hs_s[128*64];   // 16 KB, swizzled
    __shared__ __align__(16) unsigned short ts_s[128*64];   // 16 KB, swizzled
    __shared__ __align__(16) unsigned short w_s[256*64];    // 32 KB, [o][j] swizzled

    // ---- stage hs/ts tiles (rows m0..m0+127, cols kb*64..+63), pre-swizzled src ----
    #pragma unroll
    for (int q = 0; q < 4; ++q) {
        int slot = q*256 + tid;                  // 1024 slots of 16B
        int r = slot >> 3, s = slot & 7;
        int g = s ^ (r & 7);
        size_t srcoff = (size_t)(m0 + r)*EMB_ + kb*64 + (g << 3);
        char* dst = (char*)hs_s + (q*4096 + wid*1024);
        gload_lds16(hsp + srcoff, dst);
        char* dstT = (char*)ts_s + (q*4096 + wid*1024);
        gload_lds16(tsp + srcoff, dstT);
    }
    __syncthreads();

    // ---- load ts fragments to registers (once per block) ----
    u32x4 tfr[4][2];
    #pragma unroll
    for (int mf = 0; mf < 4; ++mf) {
        int r = wr*64 + mf*16 + (lane & 15);
        #pragma unroll
        for (int jh = 0; jh < 2; ++jh) {
            int s = jh*4 + (lane >> 4);
            int boffr = r*128 + ((s ^ (r & 7)) << 4);
            tfr[mf][jh] = *(const u32x4*)((const char*)ts_s + boffr);
        }
    }

    // ---- precompute B-read offsets ----
    int boff[2][8];
    #pragma unroll
    for (int jh = 0; jh < 2; ++jh)
        #pragma unroll
        for (int of = 0; of < 8; ++of) {
            int ol = wc*128 + of*16 + (lane & 15);
            int s = jh*4 + (lane >> 4);
            boff[jh][of] = ol*128 + ((s ^ (ol & 7)) << 4);
        }

    f32x4 acc[4][8];
    const f32x4 zz = {0.f, 0.f, 0.f, 0.f};
    #pragma unroll
    for (int mf = 0; mf < 4; ++mf)
        #pragma unroll
        for (int of = 0; of < 8; ++of) acc[mf][of] = zz;

    // ---- main loop over i (A-row within k-block) ----
    for (int i = 0; i < 64; ++i) {
        // stage W rows (kb*64+i)*64 + j, cols o0..o0+255 (transposed, swizzled)
        size_t kbase = (size_t)(kb*64 + i) * 64;
        #pragma unroll
        for (int q = 0; q < 8; ++q) {
            int slot = q*256 + tid;              // 2048 slots
            int o = slot >> 3, s = slot & 7;
            int g = s ^ (o & 7);
            const unsigned short* src = Wt + (size_t)(o0 + o)*KTOT_ + kbase + (g << 3);
            gload_lds16(src, (char*)w_s + (q*4096 + wid*1024));
        }
        __syncthreads();

        float hsf[4];
        #pragma unroll
        for (int mf = 0; mf < 4; ++mf) {
            int r = wr*64 + mf*16 + (lane & 15);
            int hb = r*128 + ((((i >> 3)) ^ (r & 7)) << 4) + (i & 7)*2;
            unsigned short hv = *(const unsigned short*)((const char*)hs_s + hb);
            hsf[mf] = __builtin_bit_cast(float, (uint32_t)hv << 16);
        }

        #pragma unroll
        for (int jh = 0; jh < 2; ++jh) {
            s16x8 afr[4];
            #pragma unroll
            for (int mf = 0; mf < 4; ++mf) {
                u32x4 t = tfr[mf][jh];
                u32x4 a;
                #pragma unroll
                for (int p = 0; p < 4; ++p) {
                    float lo = __builtin_bit_cast(float, t[p] << 16);
                    float hi = __builtin_bit_cast(float, t[p] & 0xffff0000u);
                    a[p] = pkbf16(hsf[mf]*lo, hsf[mf]*hi);
                }
                afr[mf] = __builtin_bit_cast(s16x8, a);
            }
            #pragma unroll
            for (int of = 0; of < 8; ++of) {
                s16x8 bfr = *(const s16x8*)((const char*)w_s + boff[jh][of]);
                #pragma unroll
                for (int mf = 0; mf < 4; ++mf)
                    acc[mf][of] = __builtin_amdgcn_mfma_f32_16x16x32_bf16(
                        afr[mf], bfr, acc[mf][of], 0, 0, 0);
            }
        }
        __syncthreads();
    }

    // ---- atomic accumulate into embeds ----
    #pragma unroll
    for (int mf = 0; mf < 4; ++mf) {
        #pragma unroll
        for (int of = 0; of < 8; ++of) {
            int col = o0 + wc*128 + of*16 + (lane & 15);
            #pragma unroll
            for (int rr = 0; rr < 4; ++rr) {
                int row = wr*64 + mf*16 + (lane >> 4)*4 + rr;
                int n = m0 + row;
                if (n < N_)
                    atomicAdd(&embeds[(size_t)n*OUT_ + col], acc[mf][of][rr]);
            }
        }
    }
}

// ---------------- class + binary logits ----------------
__global__ void k_logits(const float* __restrict__ embeds,
                         const float* __restrict__ Wc, const float* __restrict__ bc,
                         const float* __restrict__ Wbn, const float* __restrict__ bbn,
                         float* __restrict__ cls, float* __restrict__ bin)
{
    int n = blockIdx.x;
    __shared__ float row[OUT_];
    for (int o = threadIdx.x; o < OUT_; o += blockDim.x)
        row[o] = embeds[(size_t)n*OUT_ + o];
    __syncthreads();
    for (int c = threadIdx.x; c < NC_ + 1; c += blockDim.x) {
        if (c < NC_) {
            float acc = bc[c];
            for (int o = 0; o < OUT_; ++o) acc += row[o] * Wc[(size_t)o*NC_ + c];
            cls[(size_t)n*NC_ + c] = acc;
        } else {
            float acc = bbn[0];
            for (int o = 0; o < OUT_; ++o) acc += row[o] * Wbn[o];
            bin[n] = acc;
        }
    }
}

extern "C" void kernel_launch(void* const* d_in, const int* in_sizes, int n_in,
                              void* d_out, int out_size, void* d_ws, size_t ws_size,
                              hipStream_t stream) {
    const float* seq_lhs = (const float*)d_in[0];
    const float* ent_lhs = (const float*)d_in[1];
    const float* attn    = (const float*)d_in[2];
    const int*   labels  = (const int*)d_in[3];
    const int*   hts     = (const int*)d_in[4];
    const float* W_head  = (const float*)d_in[5];
    const float* b_head  = (const float*)d_in[6];
    const float* W_tail  = (const float*)d_in[7];
    const float* b_tail  = (const float*)d_in[8];
    const float* W_bil   = (const float*)d_in[9];
    const float* b_bil   = (const float*)d_in[10];
    const float* W_cls   = (const float*)d_in[11];
    const float* b_cls   = (const float*)d_in[12];
    const float* W_bin   = (const float*)d_in[13];
    const float* b_bin   = (const float*)d_in[14];

    float* out_embeds = (float*)d_out;                       // N x OUT
    float* out_cls    = out_embeds + (size_t)N_*OUT_;        // N x NC
    float* out_bin    = out_cls + (size_t)N_*NC_;            // N

    float* ws = (float*)d_ws;
    size_t off = 0;
    float* ent_emb = ws + off;        off += (size_t)B_*E_*H_;        // 98304
    float* amean   = ws + off;        off += (size_t)B_*E_*A_*L_;     // 1572864
    float* ht_attn = ws + off;        off += (size_t)B_*R_*L_;        // 2260992
    float* rel     = ws + off;        off += (size_t)N_*H_;           // 2260992
    unsigned short* hsp = (unsigned short*)(ws + off);  off += (size_t)NPAD_*EMB_/2;
    unsigned short* tsp = (unsigned short*)(ws + off);  off += (size_t)NPAD_*EMB_/2;
    unsigned short* Wt  = (unsigned short*)(ws + off);  off += (size_t)OUT_*KTOT_/2;

    // one-time-per-launch W conversion+transpose (independent of other stages)
    k_cvtW<<<dim3(KTOT_/64, OUT_/64), 256, 0, stream>>>(W_bil, Wt);

    k_pool<<<B_*E_, 256, 0, stream>>>(ent_lhs, attn, labels, ent_emb, amean);
    k_htattn<<<B_*R_, 256, 0, stream>>>(amean, hts, ht_attn);
    k_rel<<<dim3(H_/256, B_*(R_/8)), 256, 0, stream>>>(seq_lhs, ht_attn, rel);

    dim3 pgrid((N_ + 63)/64, OUT_/64);
    k_proj<<<pgrid, 256, 0, stream>>>(ent_emb, rel, hts, 0, W_head, b_head, hsp);
    k_proj<<<pgrid, 256, 0, stream>>>(ent_emb, rel, hts, 1, W_tail, b_tail, tsp);

    k_bias_init<<<(N_*OUT_ + 255)/256, 256, 0, stream>>>(b_bil, out_embeds);
    k_bilinear_mfma<<<18*3*KB_, 256, 0, stream>>>(hsp, tsp, Wt, out_embeds);

    k_logits<<<N_, 128, 0, stream>>>(out_embeds, W_cls, b_cls, W_bin, b_bin,
                                     out_cls, out_bin);
}

// Round 3
// 801.107 us; speedup vs baseline: 7.0077x; 1.6424x over previous
//
#include <hip/hip_runtime.h>
#include <hip/hip_bf16.h>
#include <math.h>
#include <stdint.h>

#define B_ 4
#define M_ 72
#define E_ 24
#define R_ 552
#define L_ 1024
#define H_ 1024
#define A_ 16
#define EMB_ 768
#define BLK_ 64
#define OUT_ 768
#define NC_ 97
#define N_ (B_*R_)        // 2208
#define NPAD_ 2304        // padded rows
#define K2H_ (2*H_)       // 2048
#define KB_ (EMB_/BLK_)   // 12
#define KTOT_ (EMB_*BLK_) // 49152

typedef short s16x8 __attribute__((ext_vector_type(8)));
typedef float f32x4 __attribute__((ext_vector_type(4)));
typedef uint32_t u32x4 __attribute__((ext_vector_type(4)));

__device__ __forceinline__ uint32_t pkbf16(float lo, float hi) {
    uint32_t r;
    asm("v_cvt_pk_bf16_f32 %0, %1, %2" : "=v"(r) : "v"(lo), "v"(hi));
    return r;
}
__device__ __forceinline__ unsigned short f2bf(float f) {
    uint32_t u = __builtin_bit_cast(uint32_t, f);
    uint32_t r = (u + 0x7fffu + ((u >> 16) & 1u)) >> 16;
    return (unsigned short)r;
}
__device__ __forceinline__ void gload_lds16(const void* g, void* l) {
    __builtin_amdgcn_global_load_lds(
        (const __attribute__((address_space(1))) unsigned int*)g,
        (__attribute__((address_space(3))) unsigned int*)l, 16, 0, 0);
}

// ---------------- pooling: ent_emb (logsumexp, bf16 out) + amean ----------------
__global__ void k_pool(const float* __restrict__ ent_lhs,  // B,M,H
                       const float* __restrict__ attn,     // B,A,M,L
                       const int*   __restrict__ labels,   // B,M
                       unsigned short* __restrict__ ent_bf,// B,E,H bf16
                       float* __restrict__ amean)          // B,E,A,L
{
    int b = blockIdx.x / E_;
    int e = blockIdx.x % E_;
    __shared__ int mlist[M_];
    __shared__ int mcount;
    if (threadIdx.x == 0) {
        int c = 0;
        for (int m = 0; m < M_; ++m)
            if (labels[b*M_ + m] == e) mlist[c++] = m;
        mcount = c;
    }
    __syncthreads();
    int cnt = mcount;

    for (int h = threadIdx.x; h < H_; h += blockDim.x) {
        float out = 0.f;
        if (cnt > 0) {
            float mx = -INFINITY;
            for (int q = 0; q < cnt; ++q)
                mx = fmaxf(mx, ent_lhs[(size_t)(b*M_ + mlist[q])*H_ + h]);
            float s = 0.f;
            for (int q = 0; q < cnt; ++q)
                s += expf(ent_lhs[(size_t)(b*M_ + mlist[q])*H_ + h] - mx);
            out = logf(s) + mx;
        }
        ent_bf[(size_t)(b*E_ + e)*H_ + h] = f2bf(out);
    }

    float inv = (cnt > 0) ? (1.f / (float)cnt) : 0.f;
    for (int c = threadIdx.x; c < A_*L_; c += blockDim.x) {
        int a = c / L_, l = c % L_;
        float s = 0.f;
        for (int q = 0; q < cnt; ++q)
            s += attn[((size_t)(b*A_ + a)*M_ + mlist[q])*L_ + l];
        amean[((size_t)(b*E_ + e)*A_ + a)*L_ + l] = s * inv;
    }
}

// ---------------- ht_attn ----------------
__global__ void k_htattn(const float* __restrict__ amean,   // B,E,A,L
                         const int*   __restrict__ hts,     // B,R,2
                         float* __restrict__ ht_attn)       // B,R,L
{
    int br = blockIdx.x;
    int b  = br / R_;
    int hh = hts[br*2 + 0], tt = hts[br*2 + 1];
    const float* pa = amean + (size_t)(b*E_ + hh)*A_*L_;
    const float* pb = amean + (size_t)(b*E_ + tt)*A_*L_;

    float vals[L_/256];
    float partial = 0.f;
    for (int i = 0, l = threadIdx.x; l < L_; l += 256, ++i) {
        float s = 0.f;
        #pragma unroll
        for (int a = 0; a < A_; ++a)
            s += pa[(size_t)a*L_ + l] * pb[(size_t)a*L_ + l];
        s *= (1.f/(float)A_);
        vals[i] = s;
        partial += s;
    }
    __shared__ float red[256];
    red[threadIdx.x] = partial;
    __syncthreads();
    for (int st = 128; st > 0; st >>= 1) {
        if (threadIdx.x < st) red[threadIdx.x] += red[threadIdx.x + st];
        __syncthreads();
    }
    float norm = 1.f / (red[0] + 1e-5f);
    for (int i = 0, l = threadIdx.x; l < L_; l += 256, ++i)
        ht_attn[(size_t)br*L_ + l] = vals[i] * norm;
}

// ---------------- rel (bf16 out) ----------------
__global__ void k_rel(const float* __restrict__ seq,   // B,L,H
                      const float* __restrict__ w,     // B,R,L
                      unsigned short* __restrict__ rel_bf) // N,H bf16
{
    int d   = blockIdx.x * 256 + threadIdx.x;
    int grp = blockIdx.y;
    int b   = grp / (R_/8);
    int r0  = (grp % (R_/8)) * 8;
    __shared__ float ws[8][256];
    float acc[8] = {0,0,0,0,0,0,0,0};
    const float* sb = seq + (size_t)b*L_*H_;
    for (int l0 = 0; l0 < L_; l0 += 256) {
        __syncthreads();
        #pragma unroll
        for (int j = 0; j < 8; ++j)
            ws[j][threadIdx.x] = w[(size_t)(b*R_ + r0 + j)*L_ + l0 + threadIdx.x];
        __syncthreads();
        for (int l = 0; l < 256; ++l) {
            float s = sb[(size_t)(l0 + l)*H_ + d];
            #pragma unroll
            for (int j = 0; j < 8; ++j) acc[j] += s * ws[j][l];
        }
    }
    #pragma unroll
    for (int j = 0; j < 8; ++j)
        rel_bf[(size_t)(b*R_ + r0 + j)*H_ + d] = f2bf(acc[j]);
}

// ---------------- W f32 [K][768] -> Wt bf16 [768][K] (transpose+cvt) ----------------
__global__ void k_cvtW(const float* __restrict__ W, unsigned short* __restrict__ Wt,
                       int Ktot)
{
    __shared__ unsigned short t[64][72];
    int k0 = blockIdx.x * 64, o0 = blockIdx.y * 64;
    #pragma unroll
    for (int p = 0; p < 16; ++p) {
        int idx = p*256 + threadIdx.x;
        int r = idx >> 6, c = idx & 63;          // r: k-local, c: o-local
        t[c][r] = f2bf(W[(size_t)(k0 + r)*OUT_ + o0 + c]);
    }
    __syncthreads();
    #pragma unroll
    for (int p = 0; p < 16; ++p) {
        int idx = p*256 + threadIdx.x;
        int r = idx >> 6, c = idx & 63;          // r: o-local, c: k-local
        Wt[(size_t)(o0 + r)*Ktot + k0 + c] = t[r][c];
    }
}

// ---------------- pacc init with bias ----------------
__global__ void k_pinit(const float* __restrict__ b_head,
                        const float* __restrict__ b_tail,
                        float* __restrict__ pacc)     // [2][NPAD][768]
{
    int idx = blockIdx.x * 256 + threadIdx.x;
    if (idx < 2*NPAD_*OUT_) {
        const float* bb = (idx < NPAD_*OUT_) ? b_head : b_tail;
        pacc[idx] = bb[idx % OUT_];
    }
}

// ---------------- fused head/tail projection MFMA GEMM ----------------
// grid: 2(which) x 18(m) x 3(o) x 4(ksplit) = 432 blocks, 256 threads (4 waves)
// BM=128, BN=256, BK=64 x 8 steps (Kslice=512), atomicAdd f32 into pacc
__global__ __launch_bounds__(256, 2)
void k_proj_mfma(const unsigned short* __restrict__ ent_bf, // B,E,H bf16
                 const unsigned short* __restrict__ rel_bf, // N,H bf16
                 const int*   __restrict__ hts,
                 const unsigned short* __restrict__ Wph,    // 768 x 2048 bf16
                 const unsigned short* __restrict__ Wpt,
                 float* __restrict__ pacc)                  // [2][NPAD][768]
{
    int bid = blockIdx.x;
    int kq = bid & 3;
    int rest = bid >> 2;
    int ob = rest % 3;  rest /= 3;
    int mb = rest % 18;
    int which = rest / 18;
    int m0 = mb * 128, o0 = ob * 256;
    const unsigned short* Wp = which ? Wpt : Wph;
    float* out = pacc + (size_t)which*NPAD_*OUT_;

    int tid = threadIdx.x, lane = tid & 63, wid = tid >> 6;
    int wr = wid >> 1, wc = wid & 1;

    __shared__ __align__(16) unsigned short a_s[128*64];   // 16 KB swizzled
    __shared__ __align__(16) unsigned short b_s[256*64];   // 32 KB swizzled

    bool enthalf = (kq < 2);
    // per-thread A-slot source bases (gather resolved once)
    const unsigned short* abase[4];
    #pragma unroll
    for (int q = 0; q < 4; ++q) {
        int slot = q*256 + tid;
        int r = slot >> 3;
        int n = m0 + r;
        int nn = (n < N_) ? n : (N_ - 1);
        if (enthalf) {
            int bb = nn / R_;
            int e = hts[nn*2 + which];
            abase[q] = ent_bf + (size_t)(bb*E_ + e)*H_;
        } else {
            abase[q] = rel_bf + (size_t)nn*H_;
        }
    }

    f32x4 acc[4][8];
    const f32x4 zz = {0.f,0.f,0.f,0.f};
    #pragma unroll
    for (int mf = 0; mf < 4; ++mf)
        #pragma unroll
        for (int of = 0; of < 8; ++of) acc[mf][of] = zz;

    int klocal0 = kq*512 - (enthalf ? 0 : 1024);
    for (int st = 0; st < 8; ++st) {
        __syncthreads();
        int klocal = klocal0 + st*64;
        #pragma unroll
        for (int q = 0; q < 4; ++q) {                 // A: 1024 slots
            int slot = q*256 + tid;
            int r = slot >> 3, s = slot & 7;
            int g = s ^ (r & 7);
            gload_lds16(abase[q] + klocal + (g << 3),
                        (char*)a_s + (q*4096 + wid*1024));
        }
        int kglob = kq*512 + st*64;
        #pragma unroll
        for (int q = 0; q < 8; ++q) {                 // B: 2048 slots
            int slot = q*256 + tid;
            int o = slot >> 3, s = slot & 7;
            int g = s ^ (o & 7);
            gload_lds16(Wp + (size_t)(o0 + o)*K2H_ + kglob + (g << 3),
                        (char*)b_s + (q*4096 + wid*1024));
        }
        __syncthreads();
        #pragma unroll
        for (int kh = 0; kh < 2; ++kh) {
            s16x8 af[4];
            #pragma unroll
            for (int mf = 0; mf < 4; ++mf) {
                int r = wr*64 + mf*16 + (lane & 15);
                int s = kh*4 + (lane >> 4);
                af[mf] = *(const s16x8*)((const char*)a_s + r*128 + ((s ^ (r & 7)) << 4));
            }
            #pragma unroll
            for (int of = 0; of < 8; ++of) {
                int ol = wc*128 + of*16 + (lane & 15);
                int s = kh*4 + (lane >> 4);
                s16x8 bfr = *(const s16x8*)((const char*)b_s + ol*128 + ((s ^ (ol & 7)) << 4));
                #pragma unroll
                for (int mf = 0; mf < 4; ++mf)
                    acc[mf][of] = __builtin_amdgcn_mfma_f32_16x16x32_bf16(
                        af[mf], bfr, acc[mf][of], 0, 0, 0);
            }
        }
    }

    #pragma unroll
    for (int mf = 0; mf < 4; ++mf)
        #pragma unroll
        for (int of = 0; of < 8; ++of) {
            int col = o0 + wc*128 + of*16 + (lane & 15);
            #pragma unroll
            for (int rr = 0; rr < 4; ++rr) {
                int row = m0 + wr*64 + mf*16 + (lane >> 4)*4 + rr;
                atomicAdd(&out[(size_t)row*OUT_ + col], acc[mf][of][rr]);
            }
        }
}

// ---------------- tanh + cvt: pacc -> hsp/tsp bf16 ----------------
__global__ void k_tanhcvt(const float* __restrict__ pacc,
                          unsigned short* __restrict__ hsp,
                          unsigned short* __restrict__ tsp)
{
    int idx = blockIdx.x * 256 + threadIdx.x;
    if (idx < NPAD_*OUT_) {
        hsp[idx] = f2bf(tanhf(pacc[idx]));
        tsp[idx] = f2bf(tanhf(pacc[NPAD_*OUT_ + idx]));
    }
}

// ---------------- embeds = bias ----------------
__global__ void k_bias_init(const float* __restrict__ bias, float* __restrict__ embeds)
{
    int idx = blockIdx.x * 256 + threadIdx.x;
    if (idx < N_*OUT_) embeds[idx] = bias[idx % OUT_];
}

// ---------------- bilinear MFMA GEMM ----------------
__global__ __launch_bounds__(256, 2)
void k_bilinear_mfma(const unsigned short* __restrict__ hsp,  // NPAD x 768 bf16
                     const unsigned short* __restrict__ tsp,  // NPAD x 768 bf16
                     const unsigned short* __restrict__ Wt,   // 768 x 49152 bf16
                     float* __restrict__ embeds)              // N x 768 (atomic +=)
{
    int bid = blockIdx.x;
    int kb = bid % KB_;
    int rest = bid / KB_;
    int ob = rest % 3;
    int mb = rest / 3;
    int m0 = mb * 128, o0 = ob * 256;
    int tid = threadIdx.x;
    int lane = tid & 63, wid = tid >> 6;
    int wr = wid >> 1, wc = wid & 1;

    __shared__ __align__(16) unsigned short hs_s[128*64];
    __shared__ __align__(16) unsigned short ts_s[128*64];
    __shared__ __align__(16) unsigned short w_s[256*64];

    #pragma unroll
    for (int q = 0; q < 4; ++q) {
        int slot = q*256 + tid;
        int r = slot >> 3, s = slot & 7;
        int g = s ^ (r & 7);
        size_t srcoff = (size_t)(m0 + r)*EMB_ + kb*64 + (g << 3);
        gload_lds16(hsp + srcoff, (char*)hs_s + (q*4096 + wid*1024));
        gload_lds16(tsp + srcoff, (char*)ts_s + (q*4096 + wid*1024));
    }
    __syncthreads();

    u32x4 tfr[4][2];
    #pragma unroll
    for (int mf = 0; mf < 4; ++mf) {
        int r = wr*64 + mf*16 + (lane & 15);
        #pragma unroll
        for (int jh = 0; jh < 2; ++jh) {
            int s = jh*4 + (lane >> 4);
            int boffr = r*128 + ((s ^ (r & 7)) << 4);
            tfr[mf][jh] = *(const u32x4*)((const char*)ts_s + boffr);
        }
    }

    int boff[2][8];
    #pragma unroll
    for (int jh = 0; jh < 2; ++jh)
        #pragma unroll
        for (int of = 0; of < 8; ++of) {
            int ol = wc*128 + of*16 + (lane & 15);
            int s = jh*4 + (lane >> 4);
            boff[jh][of] = ol*128 + ((s ^ (ol & 7)) << 4);
        }

    f32x4 acc[4][8];
    const f32x4 zz = {0.f, 0.f, 0.f, 0.f};
    #pragma unroll
    for (int mf = 0; mf < 4; ++mf)
        #pragma unroll
        for (int of = 0; of < 8; ++of) acc[mf][of] = zz;

    for (int i = 0; i < 64; ++i) {
        size_t kbase = (size_t)(kb*64 + i) * 64;
        #pragma unroll
        for (int q = 0; q < 8; ++q) {
            int slot = q*256 + tid;
            int o = slot >> 3, s = slot & 7;
            int g = s ^ (o & 7);
            gload_lds16(Wt + (size_t)(o0 + o)*KTOT_ + kbase + (g << 3),
                        (char*)w_s + (q*4096 + wid*1024));
        }
        __syncthreads();

        float hsf[4];
        #pragma unroll
        for (int mf = 0; mf < 4; ++mf) {
            int r = wr*64 + mf*16 + (lane & 15);
            int hb = r*128 + ((((i >> 3)) ^ (r & 7)) << 4) + (i & 7)*2;
            unsigned short hv = *(const unsigned short*)((const char*)hs_s + hb);
            hsf[mf] = __builtin_bit_cast(float, (uint32_t)hv << 16);
        }

        #pragma unroll
        for (int jh = 0; jh < 2; ++jh) {
            s16x8 afr[4];
            #pragma unroll
            for (int mf = 0; mf < 4; ++mf) {
                u32x4 t = tfr[mf][jh];
                u32x4 a;
                #pragma unroll
                for (int p = 0; p < 4; ++p) {
                    float lo = __builtin_bit_cast(float, t[p] << 16);
                    float hi = __builtin_bit_cast(float, t[p] & 0xffff0000u);
                    a[p] = pkbf16(hsf[mf]*lo, hsf[mf]*hi);
                }
                afr[mf] = __builtin_bit_cast(s16x8, a);
            }
            #pragma unroll
            for (int of = 0; of < 8; ++of) {
                s16x8 bfr = *(const s16x8*)((const char*)w_s + boff[jh][of]);
                #pragma unroll
                for (int mf = 0; mf < 4; ++mf)
                    acc[mf][of] = __builtin_amdgcn_mfma_f32_16x16x32_bf16(
                        afr[mf], bfr, acc[mf][of], 0, 0, 0);
            }
        }
        __syncthreads();
    }

    #pragma unroll
    for (int mf = 0; mf < 4; ++mf) {
        #pragma unroll
        for (int of = 0; of < 8; ++of) {
            int col = o0 + wc*128 + of*16 + (lane & 15);
            #pragma unroll
            for (int rr = 0; rr < 4; ++rr) {
                int row = wr*64 + mf*16 + (lane >> 4)*4 + rr;
                int n = m0 + row;
                if (n < N_)
                    atomicAdd(&embeds[(size_t)n*OUT_ + col], acc[mf][of][rr]);
            }
        }
    }
}

// ---------------- class + binary logits ----------------
__global__ void k_logits(const float* __restrict__ embeds,
                         const float* __restrict__ Wc, const float* __restrict__ bc,
                         const float* __restrict__ Wbn, const float* __restrict__ bbn,
                         float* __restrict__ cls, float* __restrict__ bin)
{
    int n = blockIdx.x;
    __shared__ float row[OUT_];
    for (int o = threadIdx.x; o < OUT_; o += blockDim.x)
        row[o] = embeds[(size_t)n*OUT_ + o];
    __syncthreads();
    for (int c = threadIdx.x; c < NC_ + 1; c += blockDim.x) {
        if (c < NC_) {
            float acc = bc[c];
            for (int o = 0; o < OUT_; ++o) acc += row[o] * Wc[(size_t)o*NC_ + c];
            cls[(size_t)n*NC_ + c] = acc;
        } else {
            float acc = bbn[0];
            for (int o = 0; o < OUT_; ++o) acc += row[o] * Wbn[o];
            bin[n] = acc;
        }
    }
}

extern "C" void kernel_launch(void* const* d_in, const int* in_sizes, int n_in,
                              void* d_out, int out_size, void* d_ws, size_t ws_size,
                              hipStream_t stream) {
    const float* seq_lhs = (const float*)d_in[0];
    const float* ent_lhs = (const float*)d_in[1];
    const float* attn    = (const float*)d_in[2];
    const int*   labels  = (const int*)d_in[3];
    const int*   hts     = (const int*)d_in[4];
    const float* W_head  = (const float*)d_in[5];
    const float* b_head  = (const float*)d_in[6];
    const float* W_tail  = (const float*)d_in[7];
    const float* b_tail  = (const float*)d_in[8];
    const float* W_bil   = (const float*)d_in[9];
    const float* b_bil   = (const float*)d_in[10];
    const float* W_cls   = (const float*)d_in[11];
    const float* b_cls   = (const float*)d_in[12];
    const float* W_bin   = (const float*)d_in[13];
    const float* b_bin   = (const float*)d_in[14];

    float* out_embeds = (float*)d_out;
    float* out_cls    = out_embeds + (size_t)N_*OUT_;
    float* out_bin    = out_cls + (size_t)N_*NC_;

    float* ws = (float*)d_ws;
    size_t off = 0;
    unsigned short* ent_bf = (unsigned short*)(ws + off); off += (size_t)B_*E_*H_/2;   // 49152 fl
    float* pacc    = ws + off;                            // overlays amean+ht_attn
    float* amean   = ws + off;        off += (size_t)B_*E_*A_*L_;     // 1572864 fl
    float* ht_attn = ws + off;        off += (size_t)B_*R_*L_;        // 2260992 fl
    unsigned short* rel_bf = (unsigned short*)(ws + off); off += (size_t)N_*H_/2;      // 1130496 fl
    unsigned short* hsp = (unsigned short*)(ws + off);  off += (size_t)NPAD_*EMB_/2;
    unsigned short* tsp = (unsigned short*)(ws + off);  off += (size_t)NPAD_*EMB_/2;
    unsigned short* Wt  = (unsigned short*)(ws + off);  off += (size_t)OUT_*KTOT_/2;
    unsigned short* Wph = (unsigned short*)(ws + off);  off += (size_t)OUT_*K2H_/2;
    unsigned short* Wpt = (unsigned short*)(ws + off);  off += (size_t)OUT_*K2H_/2;

    // weight conversions (independent of activation pipeline)
    k_cvtW<<<dim3(KTOT_/64, OUT_/64), 256, 0, stream>>>(W_bil, Wt, KTOT_);
    k_cvtW<<<dim3(K2H_/64, OUT_/64), 256, 0, stream>>>(W_head, Wph, K2H_);
    k_cvtW<<<dim3(K2H_/64, OUT_/64), 256, 0, stream>>>(W_tail, Wpt, K2H_);

    k_pool<<<B_*E_, 256, 0, stream>>>(ent_lhs, attn, labels, ent_bf, amean);
    k_htattn<<<B_*R_, 256, 0, stream>>>(amean, hts, ht_attn);
    k_rel<<<dim3(H_/256, B_*(R_/8)), 256, 0, stream>>>(seq_lhs, ht_attn, rel_bf);

    // pacc overlays amean/ht_attn -- init only after k_rel consumed them
    k_pinit<<<(2*NPAD_*OUT_ + 255)/256, 256, 0, stream>>>(b_head, b_tail, pacc);
    k_proj_mfma<<<2*18*3*4, 256, 0, stream>>>(ent_bf, rel_bf, hts, Wph, Wpt, pacc);
    k_tanhcvt<<<(NPAD_*OUT_ + 255)/256, 256, 0, stream>>>(pacc, hsp, tsp);

    k_bias_init<<<(N_*OUT_ + 255)/256, 256, 0, stream>>>(b_bil, out_embeds);
    k_bilinear_mfma<<<18*3*KB_, 256, 0, stream>>>(hsp, tsp, Wt, out_embeds);

    k_logits<<<N_, 128, 0, stream>>>(out_embeds, W_cls, b_cls, W_bin, b_bin,
                                     out_cls, out_bin);
}

// Round 4
// 671.052 us; speedup vs baseline: 8.3658x; 1.1938x over previous
//
#include <hip/hip_runtime.h>
#include <hip/hip_bf16.h>
#include <math.h>
#include <stdint.h>

#define B_ 4
#define M_ 72
#define E_ 24
#define R_ 552
#define L_ 1024
#define H_ 1024
#define A_ 16
#define EMB_ 768
#define BLK_ 64
#define OUT_ 768
#define NC_ 97
#define N_ (B_*R_)        // 2208
#define NPAD_ 2304
#define K2H_ (2*H_)       // 2048
#define KB_ (EMB_/BLK_)   // 12
#define KTOT_ (EMB_*BLK_) // 49152

typedef short s16x8 __attribute__((ext_vector_type(8)));
typedef float f32x4 __attribute__((ext_vector_type(4)));
typedef uint32_t u32x4 __attribute__((ext_vector_type(4)));

__device__ __forceinline__ uint32_t pkbf16(float lo, float hi) {
    uint32_t r;
    asm("v_cvt_pk_bf16_f32 %0, %1, %2" : "=v"(r) : "v"(lo), "v"(hi));
    return r;
}
__device__ __forceinline__ unsigned short f2bf(float f) {
    uint32_t u = __builtin_bit_cast(uint32_t, f);
    uint32_t r = (u + 0x7fffu + ((u >> 16) & 1u)) >> 16;
    return (unsigned short)r;
}
__device__ __forceinline__ float bff(unsigned short u) {
    return __builtin_bit_cast(float, (uint32_t)u << 16);
}
__device__ __forceinline__ void gload_lds16(const void* g, void* l) {
    __builtin_amdgcn_global_load_lds(
        (const __attribute__((address_space(1))) unsigned int*)g,
        (__attribute__((address_space(3))) unsigned int*)l, 16, 0, 0);
}

// ---------------- pooling: ent_emb (logsumexp, bf16) + amean (bf16) ----------------
__global__ void k_pool(const float* __restrict__ ent_lhs,
                       const float* __restrict__ attn,
                       const int*   __restrict__ labels,
                       unsigned short* __restrict__ ent_bf,   // B,E,H
                       unsigned short* __restrict__ amean_bf) // B,E,A,L
{
    int b = blockIdx.x / E_;
    int e = blockIdx.x % E_;
    __shared__ int mlist[M_];
    __shared__ int mcount;
    if (threadIdx.x == 0) {
        int c = 0;
        for (int m = 0; m < M_; ++m)
            if (labels[b*M_ + m] == e) mlist[c++] = m;
        mcount = c;
    }
    __syncthreads();
    int cnt = mcount;

    for (int h = threadIdx.x; h < H_; h += blockDim.x) {
        float out = 0.f;
        if (cnt > 0) {
            float mx = -INFINITY;
            for (int q = 0; q < cnt; ++q)
                mx = fmaxf(mx, ent_lhs[(size_t)(b*M_ + mlist[q])*H_ + h]);
            float s = 0.f;
            for (int q = 0; q < cnt; ++q)
                s += expf(ent_lhs[(size_t)(b*M_ + mlist[q])*H_ + h] - mx);
            out = logf(s) + mx;
        }
        ent_bf[(size_t)(b*E_ + e)*H_ + h] = f2bf(out);
    }

    float inv = (cnt > 0) ? (1.f / (float)cnt) : 0.f;
    for (int c = threadIdx.x; c < A_*L_; c += blockDim.x) {
        int a = c / L_, l = c % L_;
        float s = 0.f;
        for (int q = 0; q < cnt; ++q)
            s += attn[((size_t)(b*A_ + a)*M_ + mlist[q])*L_ + l];
        amean_bf[((size_t)(b*E_ + e)*A_ + a)*L_ + l] = f2bf(s * inv);
    }
}

// ---------------- ht_attn (bf16 in/out) ----------------
__global__ void k_htattn(const unsigned short* __restrict__ amean_bf, // B,E,A,L
                         const int* __restrict__ hts,
                         unsigned short* __restrict__ htw_bf)         // B,R,L
{
    int br = blockIdx.x;
    int b  = br / R_;
    int hh = hts[br*2 + 0], tt = hts[br*2 + 1];
    const unsigned short* pa = amean_bf + (size_t)(b*E_ + hh)*A_*L_;
    const unsigned short* pb = amean_bf + (size_t)(b*E_ + tt)*A_*L_;

    int l0 = threadIdx.x * 4;
    float v[4] = {0.f, 0.f, 0.f, 0.f};
    for (int a = 0; a < A_; ++a) {
        ushort4 ua = *(const ushort4*)(pa + (size_t)a*L_ + l0);
        ushort4 ub = *(const ushort4*)(pb + (size_t)a*L_ + l0);
        v[0] += bff(ua.x)*bff(ub.x); v[1] += bff(ua.y)*bff(ub.y);
        v[2] += bff(ua.z)*bff(ub.z); v[3] += bff(ua.w)*bff(ub.w);
    }
    float part = (v[0]+v[1]+v[2]+v[3]) * 0.0625f;
    __shared__ float red[256];
    red[threadIdx.x] = part;
    __syncthreads();
    for (int st = 128; st > 0; st >>= 1) {
        if (threadIdx.x < st) red[threadIdx.x] += red[threadIdx.x + st];
        __syncthreads();
    }
    float norm = 0.0625f / (red[0] + 1e-5f);
    unsigned short* po = htw_bf + (size_t)br*L_ + l0;
    po[0] = f2bf(v[0]*norm); po[1] = f2bf(v[1]*norm);
    po[2] = f2bf(v[2]*norm); po[3] = f2bf(v[3]*norm);
}

// ---------------- generic transpose+cvt: in f32 [z][K][O] -> out bf16 [z][O][K] ----------------
__global__ void k_transcvt(const float* __restrict__ W, unsigned short* __restrict__ Wt,
                           int K, int O)
{
    const float* src = W + (size_t)blockIdx.z*K*O;
    unsigned short* dst = Wt + (size_t)blockIdx.z*K*O;
    __shared__ unsigned short t[64][72];
    int k0 = blockIdx.x * 64, o0 = blockIdx.y * 64;
    #pragma unroll
    for (int p = 0; p < 16; ++p) {
        int idx = p*256 + threadIdx.x;
        int r = idx >> 6, c = idx & 63;
        t[c][r] = f2bf(src[(size_t)(k0 + r)*O + o0 + c]);
    }
    __syncthreads();
    #pragma unroll
    for (int p = 0; p < 16; ++p) {
        int idx = p*256 + threadIdx.x;
        int r = idx >> 6, c = idx & 63;
        dst[(size_t)(o0 + r)*K + k0 + c] = t[r][c];
    }
}

// ---------------- Wcls|Wbin -> WcatT bf16 [256][768] (rows >=98 zero) ----------------
__global__ void k_cvtWcat(const float* __restrict__ Wc, const float* __restrict__ Wbn,
                          unsigned short* __restrict__ WcatT)
{
    int idx = blockIdx.x*256 + threadIdx.x;
    if (idx < 256*768) {
        int o = idx / 768, k = idx % 768;
        float v = 0.f;
        if (o < NC_) v = Wc[(size_t)k*NC_ + o];
        else if (o == NC_) v = Wbn[k];
        WcatT[idx] = f2bf(v);
    }
}

// ---------------- rel = ht_attn @ seq : MFMA, reg-prefetch pipeline ----------------
// grid: 4b x 5mt x 4ot = 80 blocks; BM=128, BN=256, K=1024 (16 steps)
__global__ __launch_bounds__(256, 2)
void k_rel_mfma(const unsigned short* __restrict__ htw,   // B,R,L
                const unsigned short* __restrict__ seqT,  // B,H,L
                unsigned short* __restrict__ rel_bf)      // N,H
{
    int bid = blockIdx.x;
    int ot = bid & 3;
    int rest = bid >> 2;
    int mt = rest % 5;
    int b  = rest / 5;
    int m0 = mt*128, o0 = ot*256;
    int tid = threadIdx.x, lane = tid & 63, wid = tid >> 6;
    int wr = wid >> 1, wc = wid & 1;
    __shared__ __align__(16) unsigned short a_s[128*64];
    __shared__ __align__(16) unsigned short b_s[256*64];
    const unsigned short* Ab = htw + (size_t)b*R_*L_;
    const unsigned short* Bb = seqT + (size_t)b*H_*L_;

    u32x4 aR[4], bR[8];
    auto loadA = [&](int st) {
        #pragma unroll
        for (int q = 0; q < 4; ++q) {
            int slot = q*256 + tid;
            int r = slot >> 3, s = slot & 7;
            int ar = m0 + r; if (ar > R_-1) ar = R_-1;
            aR[q] = *(const u32x4*)(Ab + (size_t)ar*L_ + st*64 + s*8);
        }
    };
    auto loadB = [&](int st) {
        #pragma unroll
        for (int q = 0; q < 8; ++q) {
            int slot = q*256 + tid;
            int o = slot >> 3, s = slot & 7;
            bR[q] = *(const u32x4*)(Bb + (size_t)(o0+o)*L_ + st*64 + s*8);
        }
    };

    f32x4 acc[4][8];
    const f32x4 zz = {0.f,0.f,0.f,0.f};
    #pragma unroll
    for (int mf = 0; mf < 4; ++mf)
        #pragma unroll
        for (int of = 0; of < 8; ++of) acc[mf][of] = zz;

    loadA(0); loadB(0);
    for (int st = 0; st < 16; ++st) {
        __syncthreads();
        #pragma unroll
        for (int q = 0; q < 4; ++q) {
            int slot = q*256 + tid; int r = slot >> 3, s = slot & 7;
            *(u32x4*)((char*)a_s + r*128 + ((s ^ (r & 7)) << 4)) = aR[q];
        }
        #pragma unroll
        for (int q = 0; q < 8; ++q) {
            int slot = q*256 + tid; int o = slot >> 3, s = slot & 7;
            *(u32x4*)((char*)b_s + o*128 + ((s ^ (o & 7)) << 4)) = bR[q];
        }
        __syncthreads();
        if (st < 15) { loadA(st+1); loadB(st+1); }
        #pragma unroll
        for (int kh = 0; kh < 2; ++kh) {
            s16x8 af[4];
            #pragma unroll
            for (int mf = 0; mf < 4; ++mf) {
                int r = wr*64 + mf*16 + (lane & 15);
                int s = kh*4 + (lane >> 4);
                af[mf] = *(const s16x8*)((const char*)a_s + r*128 + ((s ^ (r & 7)) << 4));
            }
            #pragma unroll
            for (int of = 0; of < 8; ++of) {
                int ol = wc*128 + of*16 + (lane & 15);
                int s = kh*4 + (lane >> 4);
                s16x8 bfr = *(const s16x8*)((const char*)b_s + ol*128 + ((s ^ (ol & 7)) << 4));
                #pragma unroll
                for (int mf = 0; mf < 4; ++mf)
                    acc[mf][of] = __builtin_amdgcn_mfma_f32_16x16x32_bf16(
                        af[mf], bfr, acc[mf][of], 0, 0, 0);
            }
        }
    }
    #pragma unroll
    for (int mf = 0; mf < 4; ++mf)
        #pragma unroll
        for (int of = 0; of < 8; ++of) {
            int col = o0 + wc*128 + of*16 + (lane & 15);
            #pragma unroll
            for (int rr = 0; rr < 4; ++rr) {
                int row = m0 + wr*64 + mf*16 + (lane >> 4)*4 + rr;
                if (row < R_)
                    rel_bf[((size_t)b*R_ + row)*H_ + col] = f2bf(acc[mf][of][rr]);
            }
        }
}

// ---------------- pacc init with bias ----------------
__global__ void k_pinit(const float* __restrict__ b_head,
                        const float* __restrict__ b_tail,
                        float* __restrict__ pacc)
{
    int idx = blockIdx.x * 256 + threadIdx.x;
    if (idx < 2*NPAD_*OUT_) {
        const float* bb = (idx < NPAD_*OUT_) ? b_head : b_tail;
        pacc[idx] = bb[idx % OUT_];
    }
}

// ---------------- head/tail projection MFMA, reg-prefetch ----------------
// grid: 2 x 18 x 3 x 4 = 432 blocks
__global__ __launch_bounds__(256, 2)
void k_proj_mfma(const unsigned short* __restrict__ ent_bf,
                 const unsigned short* __restrict__ rel_bf,
                 const int* __restrict__ hts,
                 const unsigned short* __restrict__ Wph,   // 768 x 2048
                 const unsigned short* __restrict__ Wpt,
                 float* __restrict__ pacc)
{
    int bid = blockIdx.x;
    int kq = bid & 3;
    int rest = bid >> 2;
    int ob = rest % 3;  rest /= 3;
    int mb = rest % 18;
    int which = rest / 18;
    int m0 = mb * 128, o0 = ob * 256;
    const unsigned short* Wp = which ? Wpt : Wph;
    float* out = pacc + (size_t)which*NPAD_*OUT_;
    int tid = threadIdx.x, lane = tid & 63, wid = tid >> 6;
    int wr = wid >> 1, wc = wid & 1;
    __shared__ __align__(16) unsigned short a_s[128*64];
    __shared__ __align__(16) unsigned short b_s[256*64];

    bool enthalf = (kq < 2);
    const unsigned short* abase[4];
    #pragma unroll
    for (int q = 0; q < 4; ++q) {
        int slot = q*256 + tid;
        int r = slot >> 3;
        int n = m0 + r;
        int nn = (n < N_) ? n : (N_ - 1);
        if (enthalf) {
            int bb = nn / R_;
            abase[q] = ent_bf + (size_t)(bb*E_ + hts[nn*2 + which])*H_ + kq*512;
        } else {
            abase[q] = rel_bf + (size_t)nn*H_ + (kq - 2)*512;
        }
    }
    u32x4 aR[4], bR[8];
    auto loadA = [&](int st) {
        #pragma unroll
        for (int q = 0; q < 4; ++q) {
            int s = (q*256 + tid) & 7;
            aR[q] = *(const u32x4*)(abase[q] + st*64 + s*8);
        }
    };
    auto loadB = [&](int st) {
        #pragma unroll
        for (int q = 0; q < 8; ++q) {
            int slot = q*256 + tid;
            int o = slot >> 3, s = slot & 7;
            bR[q] = *(const u32x4*)(Wp + (size_t)(o0+o)*K2H_ + kq*512 + st*64 + s*8);
        }
    };

    f32x4 acc[4][8];
    const f32x4 zz = {0.f,0.f,0.f,0.f};
    #pragma unroll
    for (int mf = 0; mf < 4; ++mf)
        #pragma unroll
        for (int of = 0; of < 8; ++of) acc[mf][of] = zz;

    loadA(0); loadB(0);
    for (int st = 0; st < 8; ++st) {
        __syncthreads();
        #pragma unroll
        for (int q = 0; q < 4; ++q) {
            int slot = q*256 + tid; int r = slot >> 3, s = slot & 7;
            *(u32x4*)((char*)a_s + r*128 + ((s ^ (r & 7)) << 4)) = aR[q];
        }
        #pragma unroll
        for (int q = 0; q < 8; ++q) {
            int slot = q*256 + tid; int o = slot >> 3, s = slot & 7;
            *(u32x4*)((char*)b_s + o*128 + ((s ^ (o & 7)) << 4)) = bR[q];
        }
        __syncthreads();
        if (st < 7) { loadA(st+1); loadB(st+1); }
        #pragma unroll
        for (int kh = 0; kh < 2; ++kh) {
            s16x8 af[4];
            #pragma unroll
            for (int mf = 0; mf < 4; ++mf) {
                int r = wr*64 + mf*16 + (lane & 15);
                int s = kh*4 + (lane >> 4);
                af[mf] = *(const s16x8*)((const char*)a_s + r*128 + ((s ^ (r & 7)) << 4));
            }
            #pragma unroll
            for (int of = 0; of < 8; ++of) {
                int ol = wc*128 + of*16 + (lane & 15);
                int s = kh*4 + (lane >> 4);
                s16x8 bfr = *(const s16x8*)((const char*)b_s + ol*128 + ((s ^ (ol & 7)) << 4));
                #pragma unroll
                for (int mf = 0; mf < 4; ++mf)
                    acc[mf][of] = __builtin_amdgcn_mfma_f32_16x16x32_bf16(
                        af[mf], bfr, acc[mf][of], 0, 0, 0);
            }
        }
    }
    #pragma unroll
    for (int mf = 0; mf < 4; ++mf)
        #pragma unroll
        for (int of = 0; of < 8; ++of) {
            int col = o0 + wc*128 + of*16 + (lane & 15);
            #pragma unroll
            for (int rr = 0; rr < 4; ++rr) {
                int row = m0 + wr*64 + mf*16 + (lane >> 4)*4 + rr;
                atomicAdd(&out[(size_t)row*OUT_ + col], acc[mf][of][rr]);
            }
        }
}

// ---------------- tanh + cvt ----------------
__global__ void k_tanhcvt(const float* __restrict__ pacc,
                          unsigned short* __restrict__ hsp,
                          unsigned short* __restrict__ tsp)
{
    int idx = blockIdx.x * 256 + threadIdx.x;
    if (idx < NPAD_*OUT_) {
        hsp[idx] = f2bf(tanhf(pacc[idx]));
        tsp[idx] = f2bf(tanhf(pacc[NPAD_*OUT_ + idx]));
    }
}

// ---------------- embeds = bias ----------------
__global__ void k_bias_init(const float* __restrict__ bias, float* __restrict__ embeds)
{
    int idx = blockIdx.x * 256 + threadIdx.x;
    if (idx < N_*OUT_) embeds[idx] = bias[idx % OUT_];
}

// ---------------- bilinear MFMA GEMM, W reg-prefetch ----------------
__global__ __launch_bounds__(256, 2)
void k_bilinear_mfma(const unsigned short* __restrict__ hsp,
                     const unsigned short* __restrict__ tsp,
                     const unsigned short* __restrict__ Wt,   // 768 x 49152
                     float* __restrict__ embeds)
{
    int bid = blockIdx.x;
    int kb = bid % KB_;
    int rest = bid / KB_;
    int ob = rest % 3;
    int mb = rest / 3;
    int m0 = mb * 128, o0 = ob * 256;
    int tid = threadIdx.x;
    int lane = tid & 63, wid = tid >> 6;
    int wr = wid >> 1, wc = wid & 1;

    __shared__ __align__(16) unsigned short hs_s[128*64];
    __shared__ __align__(16) unsigned short ts_s[128*64];
    __shared__ __align__(16) unsigned short w_s[256*64];

    #pragma unroll
    for (int q = 0; q < 4; ++q) {
        int slot = q*256 + tid;
        int r = slot >> 3, s = slot & 7;
        int g = s ^ (r & 7);
        size_t srcoff = (size_t)(m0 + r)*EMB_ + kb*64 + (g << 3);
        gload_lds16(hsp + srcoff, (char*)hs_s + (q*4096 + wid*1024));
        gload_lds16(tsp + srcoff, (char*)ts_s + (q*4096 + wid*1024));
    }

    u32x4 wReg[8];
    auto loadW = [&](int i) {
        size_t kbase = (size_t)(kb*64 + i) * 64;
        #pragma unroll
        for (int q = 0; q < 8; ++q) {
            int slot = q*256 + tid;
            int o = slot >> 3, s = slot & 7;
            wReg[q] = *(const u32x4*)(Wt + (size_t)(o0+o)*KTOT_ + kbase + s*8);
        }
    };
    loadW(0);
    __syncthreads();   // hs_s/ts_s staged

    u32x4 tfr[4][2];
    #pragma unroll
    for (int mf = 0; mf < 4; ++mf) {
        int r = wr*64 + mf*16 + (lane & 15);
        #pragma unroll
        for (int jh = 0; jh < 2; ++jh) {
            int s = jh*4 + (lane >> 4);
            tfr[mf][jh] = *(const u32x4*)((const char*)ts_s + r*128 + ((s ^ (r & 7)) << 4));
        }
    }

    int boff[2][8];
    #pragma unroll
    for (int jh = 0; jh < 2; ++jh)
        #pragma unroll
        for (int of = 0; of < 8; ++of) {
            int ol = wc*128 + of*16 + (lane & 15);
            int s = jh*4 + (lane >> 4);
            boff[jh][of] = ol*128 + ((s ^ (ol & 7)) << 4);
        }

    f32x4 acc[4][8];
    const f32x4 zz = {0.f, 0.f, 0.f, 0.f};
    #pragma unroll
    for (int mf = 0; mf < 4; ++mf)
        #pragma unroll
        for (int of = 0; of < 8; ++of) acc[mf][of] = zz;

    for (int i = 0; i < 64; ++i) {
        __syncthreads();          // prev readers done with w_s; wReg(i) landed
        #pragma unroll
        for (int q = 0; q < 8; ++q) {
            int slot = q*256 + tid;
            int o = slot >> 3, s = slot & 7;
            *(u32x4*)((char*)w_s + o*128 + ((s ^ (o & 7)) << 4)) = wReg[q];
        }
        __syncthreads();
        if (i < 63) loadW(i+1);   // overlap with compute below

        float hsf[4];
        #pragma unroll
        for (int mf = 0; mf < 4; ++mf) {
            int r = wr*64 + mf*16 + (lane & 15);
            int hb = r*128 + ((((i >> 3)) ^ (r & 7)) << 4) + (i & 7)*2;
            unsigned short hv = *(const unsigned short*)((const char*)hs_s + hb);
            hsf[mf] = bff(hv);
        }

        #pragma unroll
        for (int jh = 0; jh < 2; ++jh) {
            s16x8 afr[4];
            #pragma unroll
            for (int mf = 0; mf < 4; ++mf) {
                u32x4 t = tfr[mf][jh];
                u32x4 a;
                #pragma unroll
                for (int p = 0; p < 4; ++p) {
                    float lo = __builtin_bit_cast(float, t[p] << 16);
                    float hi = __builtin_bit_cast(float, t[p] & 0xffff0000u);
                    a[p] = pkbf16(hsf[mf]*lo, hsf[mf]*hi);
                }
                afr[mf] = __builtin_bit_cast(s16x8, a);
            }
            #pragma unroll
            for (int of = 0; of < 8; ++of) {
                s16x8 bfr = *(const s16x8*)((const char*)w_s + boff[jh][of]);
                #pragma unroll
                for (int mf = 0; mf < 4; ++mf)
                    acc[mf][of] = __builtin_amdgcn_mfma_f32_16x16x32_bf16(
                        afr[mf], bfr, acc[mf][of], 0, 0, 0);
            }
        }
    }

    #pragma unroll
    for (int mf = 0; mf < 4; ++mf) {
        #pragma unroll
        for (int of = 0; of < 8; ++of) {
            int col = o0 + wc*128 + of*16 + (lane & 15);
            #pragma unroll
            for (int rr = 0; rr < 4; ++rr) {
                int row = wr*64 + mf*16 + (lane >> 4)*4 + rr;
                int n = m0 + row;
                if (n < N_)
                    atomicAdd(&embeds[(size_t)n*OUT_ + col], acc[mf][of][rr]);
            }
        }
    }
}

// ---------------- embeds f32 -> bf16 ----------------
__global__ void k_cvtemb(const float* __restrict__ embeds, unsigned short* __restrict__ emb_bf)
{
    int idx = blockIdx.x * 256 + threadIdx.x;
    if (idx < N_*OUT_) emb_bf[idx] = f2bf(embeds[idx]);
}

// ---------------- logits MFMA: [cls|bin] = emb_bf @ WcatT^T + bias ----------------
// grid: 18 blocks; BM=128, BN=256 (cols>=98 discarded), K=768 (12 steps)
__global__ __launch_bounds__(256, 2)
void k_logits_mfma(const unsigned short* __restrict__ emb_bf,  // N x 768
                   const unsigned short* __restrict__ WcatT,   // 256 x 768
                   const float* __restrict__ bc, const float* __restrict__ bbn,
                   float* __restrict__ cls, float* __restrict__ bin)
{
    int m0 = blockIdx.x * 128;
    int tid = threadIdx.x, lane = tid & 63, wid = tid >> 6;
    int wr = wid >> 1, wc = wid & 1;
    __shared__ __align__(16) unsigned short a_s[128*64];
    __shared__ __align__(16) unsigned short b_s[256*64];

    u32x4 aR[4], bR[8];
    auto loadA = [&](int st) {
        #pragma unroll
        for (int q = 0; q < 4; ++q) {
            int slot = q*256 + tid;
            int r = slot >> 3, s = slot & 7;
            int ar = m0 + r; if (ar > N_-1) ar = N_-1;
            aR[q] = *(const u32x4*)(emb_bf + (size_t)ar*OUT_ + st*64 + s*8);
        }
    };
    auto loadB = [&](int st) {
        #pragma unroll
        for (int q = 0; q < 8; ++q) {
            int slot = q*256 + tid;
            int o = slot >> 3, s = slot & 7;
            bR[q] = *(const u32x4*)(WcatT + (size_t)o*OUT_ + st*64 + s*8);
        }
    };

    f32x4 acc[4][8];
    const f32x4 zz = {0.f,0.f,0.f,0.f};
    #pragma unroll
    for (int mf = 0; mf < 4; ++mf)
        #pragma unroll
        for (int of = 0; of < 8; ++of) acc[mf][of] = zz;

    loadA(0); loadB(0);
    for (int st = 0; st < 12; ++st) {
        __syncthreads();
        #pragma unroll
        for (int q = 0; q < 4; ++q) {
            int slot = q*256 + tid; int r = slot >> 3, s = slot & 7;
            *(u32x4*)((char*)a_s + r*128 + ((s ^ (r & 7)) << 4)) = aR[q];
        }
        #pragma unroll
        for (int q = 0; q < 8; ++q) {
            int slot = q*256 + tid; int o = slot >> 3, s = slot & 7;
            *(u32x4*)((char*)b_s + o*128 + ((s ^ (o & 7)) << 4)) = bR[q];
        }
        __syncthreads();
        if (st < 11) { loadA(st+1); loadB(st+1); }
        #pragma unroll
        for (int kh = 0; kh < 2; ++kh) {
            s16x8 af[4];
            #pragma unroll
            for (int mf = 0; mf < 4; ++mf) {
                int r = wr*64 + mf*16 + (lane & 15);
                int s = kh*4 + (lane >> 4);
                af[mf] = *(const s16x8*)((const char*)a_s + r*128 + ((s ^ (r & 7)) << 4));
            }
            #pragma unroll
            for (int of = 0; of < 8; ++of) {
                int ol = wc*128 + of*16 + (lane & 15);
                int s = kh*4 + (lane >> 4);
                s16x8 bfr = *(const s16x8*)((const char*)b_s + ol*128 + ((s ^ (ol & 7)) << 4));
                #pragma unroll
                for (int mf = 0; mf < 4; ++mf)
                    acc[mf][of] = __builtin_amdgcn_mfma_f32_16x16x32_bf16(
                        af[mf], bfr, acc[mf][of], 0, 0, 0);
            }
        }
    }
    #pragma unroll
    for (int mf = 0; mf < 4; ++mf)
        #pragma unroll
        for (int of = 0; of < 8; ++of) {
            int col = wc*128 + of*16 + (lane & 15);
            if (col <= NC_) {
                #pragma unroll
                for (int rr = 0; rr < 4; ++rr) {
                    int row = m0 + wr*64 + mf*16 + (lane >> 4)*4 + rr;
                    if (row < N_) {
                        float v = acc[mf][of][rr];
                        if (col < NC_) cls[(size_t)row*NC_ + col] = v + bc[col];
                        else           bin[row] = v + bbn[0];
                    }
                }
            }
        }
}

extern "C" void kernel_launch(void* const* d_in, const int* in_sizes, int n_in,
                              void* d_out, int out_size, void* d_ws, size_t ws_size,
                              hipStream_t stream) {
    const float* seq_lhs = (const float*)d_in[0];
    const float* ent_lhs = (const float*)d_in[1];
    const float* attn    = (const float*)d_in[2];
    const int*   labels  = (const int*)d_in[3];
    const int*   hts     = (const int*)d_in[4];
    const float* W_head  = (const float*)d_in[5];
    const float* b_head  = (const float*)d_in[6];
    const float* W_tail  = (const float*)d_in[7];
    const float* b_tail  = (const float*)d_in[8];
    const float* W_bil   = (const float*)d_in[9];
    const float* b_bil   = (const float*)d_in[10];
    const float* W_cls   = (const float*)d_in[11];
    const float* b_cls   = (const float*)d_in[12];
    const float* W_bin   = (const float*)d_in[13];
    const float* b_bin   = (const float*)d_in[14];

    float* out_embeds = (float*)d_out;
    float* out_cls    = out_embeds + (size_t)N_*OUT_;
    float* out_bin    = out_cls + (size_t)N_*NC_;

    float* ws = (float*)d_ws;
    size_t off = 0;
    unsigned short* ent_bf   = (unsigned short*)(ws + off); off += (size_t)B_*E_*H_/2;
    float* pacc = ws + off;   // overlays amean_bf + htw_bf + seqT (all dead by then)
    unsigned short* amean_bf = (unsigned short*)(ws + off); off += (size_t)B_*E_*A_*L_/2;
    unsigned short* htw_bf   = (unsigned short*)(ws + off); off += (size_t)B_*R_*L_/2;
    unsigned short* seqT     = (unsigned short*)(ws + off); off += (size_t)B_*H_*L_/2;
    unsigned short* rel_bf   = (unsigned short*)(ws + off); off += (size_t)N_*H_/2;
    unsigned short* hsp      = (unsigned short*)(ws + off); off += (size_t)NPAD_*EMB_/2;
    unsigned short* tsp      = (unsigned short*)(ws + off); off += (size_t)NPAD_*EMB_/2;
    unsigned short* Wt       = (unsigned short*)(ws + off); off += (size_t)OUT_*KTOT_/2;
    unsigned short* Wph      = (unsigned short*)(ws + off); off += (size_t)OUT_*K2H_/2;
    unsigned short* Wpt      = (unsigned short*)(ws + off); off += (size_t)OUT_*K2H_/2;
    unsigned short* WcatT    = (unsigned short*)(ws + off); off += (size_t)256*768/2;
    unsigned short* emb_bf   = (unsigned short*)(ws + off); off += (size_t)N_*OUT_/2;

    // weight / input conversions
    k_transcvt<<<dim3(KTOT_/64, OUT_/64, 1), 256, 0, stream>>>(W_bil, Wt, KTOT_, OUT_);
    k_transcvt<<<dim3(K2H_/64, OUT_/64, 1), 256, 0, stream>>>(W_head, Wph, K2H_, OUT_);
    k_transcvt<<<dim3(K2H_/64, OUT_/64, 1), 256, 0, stream>>>(W_tail, Wpt, K2H_, OUT_);
    k_transcvt<<<dim3(L_/64, H_/64, B_), 256, 0, stream>>>(seq_lhs, seqT, L_, H_);
    k_cvtWcat<<<(256*768)/256, 256, 0, stream>>>(W_cls, W_bin, WcatT);

    k_pool<<<B_*E_, 256, 0, stream>>>(ent_lhs, attn, labels, ent_bf, amean_bf);
    k_htattn<<<B_*R_, 256, 0, stream>>>(amean_bf, hts, htw_bf);
    k_rel_mfma<<<80, 256, 0, stream>>>(htw_bf, seqT, rel_bf);

    // pacc overlays amean/htw/seqT -- init only after k_rel consumed them
    k_pinit<<<(2*NPAD_*OUT_ + 255)/256, 256, 0, stream>>>(b_head, b_tail, pacc);
    k_proj_mfma<<<2*18*3*4, 256, 0, stream>>>(ent_bf, rel_bf, hts, Wph, Wpt, pacc);
    k_tanhcvt<<<(NPAD_*OUT_ + 255)/256, 256, 0, stream>>>(pacc, hsp, tsp);

    k_bias_init<<<(N_*OUT_ + 255)/256, 256, 0, stream>>>(b_bil, out_embeds);
    k_bilinear_mfma<<<18*3*KB_, 256, 0, stream>>>(hsp, tsp, Wt, out_embeds);

    k_cvtemb<<<(N_*OUT_ + 255)/256, 256, 0, stream>>>(out_embeds, emb_bf);
    k_logits_mfma<<<18, 256, 0, stream>>>(emb_bf, WcatT, b_cls, b_bin,
                                          out_cls, out_bin);
}